// Round 2
// baseline (90.426 us; speedup 1.0000x reference)
//
#include <hip/hip_runtime.h>
#include <hip/hip_bf16.h>

// Leave-one-out Gaussian-kernel regression (Nadaraya-Watson), N=4096, D_IN=4, D_OUT=3.
// out[i,c] = (sum_{j!=i} K_jic * Y[j,c]) / (sum_{j!=i} K_jic)
// K_jic = exp(-0.5*((Ft[j,c]-Fx[i,c])/h)^2),  Fx = x@W^T, Ft = train_X@W^T.
//
// Structure: pack kernel builds PK[j] = {ft0,ft1,ft2,y0,y1,y2,-,-} (32 B/row,
// two dwordx4 per j). Main kernel: 1024 blocks x 128 threads (2 waves), each
// block owns TI=4 query points; 128 threads split the j-dimension -> 32
// j-iters/thread, 12 exps per iter. Wave butterfly (6 levels) + 2-wave LDS
// combine. BLK=128 (not 256) keeps reduction at ~27% of instrs instead of 75%.

constexpr int BLK = 128;  // threads per block (2 waves)
constexpr int TI  = 4;    // query points per block

__global__ void pack_kernel(const float* __restrict__ tX,
                            const float* __restrict__ Y,
                            const float* __restrict__ W,
                            float* __restrict__ PK, int N) {
    int j = blockIdx.x * blockDim.x + threadIdx.x;
    if (j >= N) return;
    float4 v = ((const float4*)tX)[j];  // D_IN = 4
    float f0 = v.x * W[0] + v.y * W[1] + v.z * W[2]  + v.w * W[3];
    float f1 = v.x * W[4] + v.y * W[5] + v.z * W[6]  + v.w * W[7];
    float f2 = v.x * W[8] + v.y * W[9] + v.z * W[10] + v.w * W[11];
    float y0 = Y[3 * j + 0], y1 = Y[3 * j + 1], y2 = Y[3 * j + 2];
    float4* o = (float4*)(PK + 8 * j);
    o[0] = make_float4(f0, f1, f2, y0);
    o[1] = make_float4(y1, y2, 0.f, 0.f);
}

__global__ __launch_bounds__(BLK) void kde_main(const float* __restrict__ x,
                                                const float* __restrict__ W,
                                                const float* __restrict__ PK,
                                                const float* __restrict__ hptr,
                                                float* __restrict__ out, int N) {
    const int i0  = blockIdx.x * TI;
    const int tid = threadIdx.x;

    const float h = hptr[0];
    // exp(-0.5*d^2/h^2) = exp2( (-0.5*log2 e / h^2) * d^2 )
    const float scale = -0.72134752044448170368f / (h * h);

    // W is 12 floats, wave-uniform -> scalar loads
    float w[12];
#pragma unroll
    for (int k = 0; k < 12; ++k) w[k] = W[k];

    // Project this block's TI query points on the fly (broadcast loads)
    float fx[TI][3];
#pragma unroll
    for (int a = 0; a < TI; ++a) {
        float4 v = ((const float4*)x)[i0 + a];
        fx[a][0] = v.x * w[0] + v.y * w[1] + v.z * w[2]  + v.w * w[3];
        fx[a][1] = v.x * w[4] + v.y * w[5] + v.z * w[6]  + v.w * w[7];
        fx[a][2] = v.x * w[8] + v.y * w[9] + v.z * w[10] + v.w * w[11];
    }

    float num[TI][3], den[TI][3];
#pragma unroll
    for (int a = 0; a < TI; ++a)
#pragma unroll
        for (int c = 0; c < 3; ++c) { num[a][c] = 0.f; den[a][c] = 0.f; }

    const float4* PK4 = (const float4*)PK;
#pragma unroll 4
    for (int j = tid; j < N; j += BLK) {
        float4 p0 = PK4[2 * j + 0];  // ft0 ft1 ft2 y0
        float4 p1 = PK4[2 * j + 1];  // y1 y2 - -
#pragma unroll
        for (int a = 0; a < TI; ++a) {
            float d0 = p0.x - fx[a][0];
            float d1 = p0.y - fx[a][1];
            float d2 = p0.z - fx[a][2];
            float k0 = __builtin_amdgcn_exp2f(scale * d0 * d0);
            float k1 = __builtin_amdgcn_exp2f(scale * d1 * d1);
            float k2 = __builtin_amdgcn_exp2f(scale * d2 * d2);
            den[a][0] += k0; num[a][0] = fmaf(k0, p0.w, num[a][0]);
            den[a][1] += k1; num[a][1] = fmaf(k1, p1.x, num[a][1]);
            den[a][2] += k2; num[a][2] = fmaf(k2, p1.y, num[a][2]);
        }
    }

    // 64-lane wave butterfly over the 24 accumulators
#pragma unroll
    for (int a = 0; a < TI; ++a)
#pragma unroll
        for (int c = 0; c < 3; ++c) {
            float n_ = num[a][c], d_ = den[a][c];
#pragma unroll
            for (int off = 32; off > 0; off >>= 1) {
                n_ += __shfl_down(n_, off, 64);
                d_ += __shfl_down(d_, off, 64);
            }
            num[a][c] = n_; den[a][c] = d_;
        }

    // Combine the block's 2 waves through LDS
    __shared__ float s_n[2][TI * 3];
    __shared__ float s_d[2][TI * 3];
    const int lane = tid & 63, wave = tid >> 6;
    if (lane == 0) {
#pragma unroll
        for (int a = 0; a < TI; ++a)
#pragma unroll
            for (int c = 0; c < 3; ++c) {
                s_n[wave][a * 3 + c] = num[a][c];
                s_d[wave][a * 3 + c] = den[a][c];
            }
    }
    __syncthreads();

    if (tid < TI * 3) {
        const int a = tid / 3, c = tid - 3 * a;
        const int i = i0 + a;
        float n_ = s_n[0][tid] + s_n[1][tid];
        float d_ = s_d[0][tid] + s_d[1][tid];
        // leave-one-out: subtract the j==i self term
        float ft = PK[8 * i + c];
        float y  = PK[8 * i + 3 + c];
        float dd = ft - fx[a][c];
        float kii = __builtin_amdgcn_exp2f(scale * dd * dd);
        out[3 * i + c] = (n_ - kii * y) / (d_ - kii);
    }
}

extern "C" void kernel_launch(void* const* d_in, const int* in_sizes, int n_in,
                              void* d_out, int out_size, void* d_ws, size_t ws_size,
                              hipStream_t stream) {
    const float* x  = (const float*)d_in[0];  // [N,4]
    const float* tX = (const float*)d_in[1];  // [N,4]
    const float* Y  = (const float*)d_in[2];  // [N,3]
    const float* W  = (const float*)d_in[3];  // [3,4]
    const float* h  = (const float*)d_in[4];  // [1]

    const int N = in_sizes[0] / 4;
    float* PK = (float*)d_ws;  // 8*N floats = 128 KB

    pack_kernel<<<(N + 255) / 256, 256, 0, stream>>>(tX, Y, W, PK, N);
    kde_main<<<N / TI, BLK, 0, stream>>>(x, W, PK, h, (float*)d_out, N);
}

// Round 3
// 77.095 us; speedup vs baseline: 1.1729x; 1.1729x over previous
//
#include <hip/hip_runtime.h>
#include <hip/hip_bf16.h>

// Leave-one-out Gaussian-kernel regression (Nadaraya-Watson), N=4096, D_IN=4, D_OUT=3.
// out[i,c] = (sum_{j!=i} K_jic * Y[j,c]) / (sum_{j!=i} K_jic)
// K_jic = exp(-0.5*((Ft[j,c]-Fx[i,c])/h)^2),  Fx = x@W^T, Ft = train_X@W^T.
//
// Single fused kernel. Algebra: with s = -log2(e)/(2h^2),
//   K = 2^{s(ft-fx)^2} = 2^{s·ft^2} · 2^{-2s·ft·fx} · 2^{s·fx^2}.
// The last factor depends only on (i,c) => cancels in num/den. So accumulate
//   K' = 2^{ fma(w2, ft, A) },  A = (s·ft)·ft (per j),  w2 = -2s·fx (per i).
// Inner eval = 1 fma + 1 exp2 + 1 add + 1 fma = 3 VALU + 1 transcendental.
//
// Grid 512 blocks x 256 thr (2048 waves = 2/SIMD). Block owns TI=8 queries;
// threads split j. Wave butterfly + 4-wave LDS combine. Self-term subtracted
// analytically in the epilogue (recomputed from globals -- NO dynamic
// register-array indexing; that caused the round-2 scratch regression).

constexpr int BLK = 256;  // threads per block (4 waves)
constexpr int TI  = 8;    // query points per block

__global__ __launch_bounds__(BLK) void kde_fused(const float* __restrict__ x,
                                                 const float* __restrict__ tX,
                                                 const float* __restrict__ Y,
                                                 const float* __restrict__ W,
                                                 const float* __restrict__ hptr,
                                                 float* __restrict__ out, int N) {
    const int i0  = blockIdx.x * TI;
    const int tid = threadIdx.x;

    const float h = hptr[0];
    const float scale = -0.72134752044448170368f / (h * h);  // -log2(e)/(2h^2)

    // W is 12 wave-uniform floats -> scalar loads
    float w[12];
#pragma unroll
    for (int k = 0; k < 12; ++k) w[k] = W[k];

    // Per-query constants w2[a][c] = -2*scale*fx  (all static indexing)
    float w2[TI][3];
#pragma unroll
    for (int a = 0; a < TI; ++a) {
        float4 xv = ((const float4*)x)[i0 + a];
#pragma unroll
        for (int c = 0; c < 3; ++c) {
            float fx = fmaf(xv.x, w[4 * c + 0],
                       fmaf(xv.y, w[4 * c + 1],
                       fmaf(xv.z, w[4 * c + 2], xv.w * w[4 * c + 3])));
            w2[a][c] = -2.f * scale * fx;
        }
    }

    float num[TI][3], den[TI][3];
#pragma unroll
    for (int a = 0; a < TI; ++a)
#pragma unroll
        for (int c = 0; c < 3; ++c) { num[a][c] = 0.f; den[a][c] = 0.f; }

#pragma unroll 2
    for (int j = tid; j < N; j += BLK) {
        float4 tv = ((const float4*)tX)[j];
        float yv[3];
        yv[0] = Y[3 * j + 0]; yv[1] = Y[3 * j + 1]; yv[2] = Y[3 * j + 2];
        float ft[3], A[3];
#pragma unroll
        for (int c = 0; c < 3; ++c) {
            ft[c] = fmaf(tv.x, w[4 * c + 0],
                    fmaf(tv.y, w[4 * c + 1],
                    fmaf(tv.z, w[4 * c + 2], tv.w * w[4 * c + 3])));
            float v = scale * ft[c];
            A[c] = v * ft[c];
        }
#pragma unroll
        for (int a = 0; a < TI; ++a)
#pragma unroll
            for (int c = 0; c < 3; ++c) {
                float arg = fmaf(w2[a][c], ft[c], A[c]);
                float k   = __builtin_amdgcn_exp2f(arg);
                den[a][c] += k;
                num[a][c]  = fmaf(k, yv[c], num[a][c]);
            }
    }

    // 64-lane wave butterfly, then 4-wave LDS combine
    __shared__ float s_n[4][TI * 3];
    __shared__ float s_d[4][TI * 3];
    const int lane = tid & 63, wave = tid >> 6;
#pragma unroll
    for (int a = 0; a < TI; ++a)
#pragma unroll
        for (int c = 0; c < 3; ++c) {
            float n_ = num[a][c], d_ = den[a][c];
#pragma unroll
            for (int off = 32; off > 0; off >>= 1) {
                n_ += __shfl_down(n_, off, 64);
                d_ += __shfl_down(d_, off, 64);
            }
            if (lane == 0) { s_n[wave][a * 3 + c] = n_; s_d[wave][a * 3 + c] = d_; }
        }
    __syncthreads();

    if (tid < TI * 3) {
        const int a = tid / 3, c = tid - 3 * a;
        const int i = i0 + a;
        float n_ = s_n[0][tid] + s_n[1][tid] + s_n[2][tid] + s_n[3][tid];
        float d_ = s_d[0][tid] + s_d[1][tid] + s_d[2][tid] + s_d[3][tid];

        // Self-term (j==i), recomputed from globals with the SAME op order as
        // the main loop. Runtime c indexes GLOBAL W (VMEM), not a reg array.
        float4 xv = ((const float4*)x)[i];
        float fx = fmaf(xv.x, W[4 * c + 0],
                   fmaf(xv.y, W[4 * c + 1],
                   fmaf(xv.z, W[4 * c + 2], xv.w * W[4 * c + 3])));
        float w2v = -2.f * scale * fx;
        float4 tv = ((const float4*)tX)[i];
        float ft = fmaf(tv.x, W[4 * c + 0],
                   fmaf(tv.y, W[4 * c + 1],
                   fmaf(tv.z, W[4 * c + 2], tv.w * W[4 * c + 3])));
        float v  = scale * ft;
        float A  = v * ft;
        float kii = __builtin_amdgcn_exp2f(fmaf(w2v, ft, A));
        float yii = Y[3 * i + c];

        out[3 * i + c] = (n_ - kii * yii) / (d_ - kii);
    }
}

extern "C" void kernel_launch(void* const* d_in, const int* in_sizes, int n_in,
                              void* d_out, int out_size, void* d_ws, size_t ws_size,
                              hipStream_t stream) {
    const float* x  = (const float*)d_in[0];  // [N,4]
    const float* tX = (const float*)d_in[1];  // [N,4]
    const float* Y  = (const float*)d_in[2];  // [N,3]
    const float* W  = (const float*)d_in[3];  // [3,4]
    const float* h  = (const float*)d_in[4];  // [1]

    const int N = in_sizes[0] / 4;  // 4096

    kde_fused<<<N / TI, BLK, 0, stream>>>(x, tX, Y, W, h, (float*)d_out, N);
}